// Round 1
// baseline (173.599 us; speedup 1.0000x reference)
//
#include <hip/hip_runtime.h>
#include <math.h>

#define N_NODES_C 10000
#define N_EDGES_C 640000
#define DIM 128

// ---------------------------------------------------------------------------
// K1: per-node gate exp:  eg[i] = exp(x[i] . w_gate + b_gate)
//     also zeroes counts[] (saves a launch). One wave (64 lanes) per node.
// ---------------------------------------------------------------------------
__global__ void gate_kernel(const float* __restrict__ x,
                            const float* __restrict__ w_gate,
                            const float* __restrict__ b_gate,
                            float* __restrict__ eg,
                            int* __restrict__ counts, int n) {
    int wid  = (int)((blockIdx.x * blockDim.x + threadIdx.x) >> 6);
    int lane = threadIdx.x & 63;
    if (wid >= n) return;
    const float2* xr = (const float2*)(x + (size_t)wid * DIM);
    const float2* wg = (const float2*)w_gate;
    float2 a = xr[lane];
    float2 b = wg[lane];
    float v = a.x * b.x + a.y * b.y;
    #pragma unroll
    for (int off = 32; off; off >>= 1) v += __shfl_xor(v, off);
    if (lane == 0) {
        eg[wid] = expf(v + b_gate[0]);
        counts[wid] = 0;
    }
}

// ---------------------------------------------------------------------------
// K2: histogram of destination nodes
// ---------------------------------------------------------------------------
__global__ void count_kernel(const int* __restrict__ row,
                             int* __restrict__ counts, int nE) {
    int e = blockIdx.x * blockDim.x + threadIdx.x;
    if (e < nE) atomicAdd(&counts[row[e]], 1);
}

// ---------------------------------------------------------------------------
// K3: exclusive scan of counts -> offsets (and cursor copy). Single block.
//     Strip-per-thread + block-level Hillis-Steele on the 1024 strip sums.
// ---------------------------------------------------------------------------
__global__ void scan_kernel(const int* __restrict__ counts,
                            int* __restrict__ offs,
                            int* __restrict__ cursor, int n, int nE) {
    const int T = 1024;
    __shared__ int lds[T];
    int tid = threadIdx.x;
    int per = (n + T - 1) / T;
    int s = tid * per;
    int e = s + per; if (e > n) e = n;
    int sum = 0;
    for (int i = s; i < e; i++) sum += counts[i];
    lds[tid] = sum;
    __syncthreads();
    for (int off = 1; off < T; off <<= 1) {
        int t = (tid >= off) ? lds[tid - off] : 0;
        __syncthreads();
        lds[tid] += t;
        __syncthreads();
    }
    int run = lds[tid] - sum;   // exclusive prefix of strips
    for (int i = s; i < e; i++) {
        offs[i] = run;
        cursor[i] = run;
        run += counts[i];
    }
    if (tid == 0) offs[n] = nE;
}

// ---------------------------------------------------------------------------
// K4: counting-sort scatter: group source indices by destination node
// ---------------------------------------------------------------------------
__global__ void scatter_kernel(const int* __restrict__ row,
                               const int* __restrict__ col,
                               int* __restrict__ cursor,
                               int* __restrict__ scol, int nE) {
    int e = blockIdx.x * blockDim.x + threadIdx.x;
    if (e < nE) {
        int r = row[e];
        int p = atomicAdd(&cursor[r], 1);
        scol[p] = col[e];
    }
}

// ---------------------------------------------------------------------------
// K5: per-node softmax-weighted aggregation of x rows.
//     One wave per node; lane holds 2 of the 128 dims (float2 accumulator).
//     agg[n][:] = sum_e attn_e * x[col_e][:],  sArr[n] = sum_e attn_e (~1 or 0)
// ---------------------------------------------------------------------------
__global__ void agg_kernel(const float* __restrict__ x,
                           const float* __restrict__ eg,
                           const int* __restrict__ offs,
                           const int* __restrict__ scol,
                           float* __restrict__ agg,
                           float* __restrict__ sArr, int n) {
    int wid  = (int)((blockIdx.x * blockDim.x + threadIdx.x) >> 6);
    int lane = threadIdx.x & 63;
    if (wid >= n) return;
    int beg = offs[wid];
    int end = offs[wid + 1];

    // pass 1: denominator
    float denom = 0.f;
    for (int i = beg; i < end; i += 64) {
        int j = i + lane;
        float ev = (j < end) ? eg[scol[j]] : 0.f;
        #pragma unroll
        for (int off = 32; off; off >>= 1) ev += __shfl_xor(ev, off);
        denom += ev;   // identical on all lanes after butterfly
    }
    float inv = 1.f / (denom + 1e-16f);
    float s   = denom * inv;

    // pass 2: weighted gather-sum
    float2 acc = make_float2(0.f, 0.f);
    for (int i = beg; i < end; i += 64) {
        int j = i + lane;
        int   c  = (j < end) ? scol[j] : 0;
        float ev = (j < end) ? eg[c] : 0.f;
        int m = end - i; if (m > 64) m = 64;
        for (int t = 0; t < m; t++) {
            int   ct = __shfl(c, t);
            float w  = __shfl(ev, t) * inv;
            const float2* xr = (const float2*)(x + (size_t)ct * DIM);
            float2 xv = xr[lane];
            acc.x += w * xv.x;
            acc.y += w * xv.y;
        }
    }
    ((float2*)(agg + (size_t)wid * DIM))[lane] = acc;
    if (lane == 0) sArr[wid] = s;
}

// ---------------------------------------------------------------------------
// K6: fold the two linear layers:  Wc[o][i] = sum_k W_out[o][k]*W_lin[k][i]
//     stored transposed WcT[i*128+o];  bc[o] = sum_k W_out[o][k]*b_lin[k]
//     Block o (128 blocks), 128 threads (i).
// ---------------------------------------------------------------------------
__global__ void wc_kernel(const float* __restrict__ W_out,
                          const float* __restrict__ W_lin,
                          const float* __restrict__ b_lin,
                          float* __restrict__ WcT,
                          float* __restrict__ bc) {
    int o = blockIdx.x;
    int i = threadIdx.x;
    __shared__ float wrow[DIM];
    __shared__ float red[DIM];
    wrow[i] = W_out[o * DIM + i];
    __syncthreads();
    float acc = 0.f;
    #pragma unroll 8
    for (int k = 0; k < DIM; k++) acc += wrow[k] * W_lin[k * DIM + i];
    WcT[i * DIM + o] = acc;
    red[i] = wrow[i] * b_lin[i];
    __syncthreads();
    for (int off = 64; off; off >>= 1) {
        if (i < off) red[i] += red[i + off];
        __syncthreads();
    }
    if (i == 0) bc[o] = red[0];
}

// ---------------------------------------------------------------------------
// K7: out[n][o] = sum_i agg[n][i] * Wc[o][i]  + s[n]*bc[o] + b_out[o]
//     256 threads = 2 groups of 128; each group does 4 nodes at a time to
//     amortize the Wc reads (L2-resident, 64KB). agg rows staged in LDS
//     (broadcast reads). High occupancy (tiny LDS) hides L2 latency.
// ---------------------------------------------------------------------------
__global__ void out_kernel(const float* __restrict__ agg,
                           const float* __restrict__ sArr,
                           const float* __restrict__ WcT,
                           const float* __restrict__ bc,
                           const float* __restrict__ b_out,
                           float* __restrict__ out, int n) {
    __shared__ float aggL[2][4][DIM];
    __shared__ float sL[2][4];
    int grp = threadIdx.x >> 7;     // 0 or 1
    int o   = threadIdx.x & 127;
    float bcv = bc[o];
    float bov = b_out[o];

    int b0 = blockIdx.x * 8;        // this block's first node
    int node0 = b0 + grp * 4;
    // stage 4 agg rows per group
    #pragma unroll
    for (int t = 0; t < 4; t++) {
        int node = node0 + t;
        aggL[grp][t][o] = (node < n) ? agg[(size_t)node * DIM + o] : 0.f;
    }
    if (o < 4) {
        int node = node0 + o;
        sL[grp][o] = (node < n) ? sArr[node] : 0.f;
    }
    __syncthreads();

    float a0 = 0.f, a1 = 0.f, a2 = 0.f, a3 = 0.f;
    #pragma unroll 4
    for (int i = 0; i < DIM; i++) {
        float w = WcT[i * DIM + o];     // coalesced 512B/wave, L2-resident
        a0 += w * aggL[grp][0][i];      // LDS broadcast
        a1 += w * aggL[grp][1][i];
        a2 += w * aggL[grp][2][i];
        a3 += w * aggL[grp][3][i];
    }
    if (node0 + 0 < n) out[(size_t)(node0 + 0) * DIM + o] = a0 + sL[grp][0] * bcv + bov;
    if (node0 + 1 < n) out[(size_t)(node0 + 1) * DIM + o] = a1 + sL[grp][1] * bcv + bov;
    if (node0 + 2 < n) out[(size_t)(node0 + 2) * DIM + o] = a2 + sL[grp][2] * bcv + bov;
    if (node0 + 3 < n) out[(size_t)(node0 + 3) * DIM + o] = a3 + sL[grp][3] * bcv + bov;
}

// ---------------------------------------------------------------------------
extern "C" void kernel_launch(void* const* d_in, const int* in_sizes, int n_in,
                              void* d_out, int out_size, void* d_ws, size_t ws_size,
                              hipStream_t stream) {
    const float* x      = (const float*)d_in[0];
    const int*   eidx   = (const int*)d_in[1];   // [2, nE] int
    // d_in[2] = batch (unused)
    const float* W_lin  = (const float*)d_in[3];
    const float* b_lin  = (const float*)d_in[4];
    const float* W_gate = (const float*)d_in[5];
    const float* b_gate = (const float*)d_in[6];
    const float* W_out  = (const float*)d_in[7];
    const float* b_out  = (const float*)d_in[8];
    float* out = (float*)d_out;

    const int n  = N_NODES_C;
    const int nE = N_EDGES_C;
    const int* row = eidx;
    const int* col = eidx + nE;

    // workspace carve-up (256B aligned), ~8 MB total
    char* ws = (char*)d_ws;
    size_t off = 0;
    auto carve = [&](size_t bytes) -> char* {
        char* p = ws + off;
        off += (bytes + 255) & ~(size_t)255;
        return p;
    };
    float* eg     = (float*)carve((size_t)n * 4);
    int*   counts = (int*)  carve((size_t)n * 4);
    int*   offs   = (int*)  carve((size_t)(n + 1) * 4);
    int*   cursor = (int*)  carve((size_t)(n + 1) * 4);
    float* sArr   = (float*)carve((size_t)n * 4);
    int*   scol   = (int*)  carve((size_t)nE * 4);
    float* agg    = (float*)carve((size_t)n * DIM * 4);
    float* WcT    = (float*)carve((size_t)DIM * DIM * 4);
    float* bc     = (float*)carve((size_t)DIM * 4);

    const int edgeBlocks = (nE + 255) / 256;          // 2500
    const int waveBlocks = ((n * 64) + 255) / 256;    // 2500

    gate_kernel   <<<waveBlocks, 256, 0, stream>>>(x, W_gate, b_gate, eg, counts, n);
    count_kernel  <<<edgeBlocks, 256, 0, stream>>>(row, counts, nE);
    scan_kernel   <<<1, 1024, 0, stream>>>(counts, offs, cursor, n, nE);
    scatter_kernel<<<edgeBlocks, 256, 0, stream>>>(row, col, cursor, scol, nE);
    agg_kernel    <<<waveBlocks, 256, 0, stream>>>(x, eg, offs, scol, agg, sArr, n);
    wc_kernel     <<<DIM, DIM, 0, stream>>>(W_out, W_lin, b_lin, WcT, bc);
    out_kernel    <<<(n + 7) / 8, 256, 0, stream>>>(agg, sArr, WcT, bc, b_out, out, n);
}

// Round 2
// 154.362 us; speedup vs baseline: 1.1246x; 1.1246x over previous
//
#include <hip/hip_runtime.h>
#include <math.h>

#define N_NODES_C 10000
#define N_EDGES_C 640000
#define DIM 128

// ---------------------------------------------------------------------------
// K1: per-node gate exp:  eg[i] = exp(x[i] . w_gate + b_gate)
//     also zeroes counts[]. One wave (64 lanes) per node.
// ---------------------------------------------------------------------------
__global__ void gate_kernel(const float* __restrict__ x,
                            const float* __restrict__ w_gate,
                            const float* __restrict__ b_gate,
                            float* __restrict__ eg,
                            int* __restrict__ counts, int n) {
    int wid  = (int)((blockIdx.x * blockDim.x + threadIdx.x) >> 6);
    int lane = threadIdx.x & 63;
    if (wid >= n) return;
    const float2* xr = (const float2*)(x + (size_t)wid * DIM);
    const float2* wg = (const float2*)w_gate;
    float2 a = xr[lane];
    float2 b = wg[lane];
    float v = a.x * b.x + a.y * b.y;
    #pragma unroll
    for (int off = 32; off; off >>= 1) v += __shfl_xor(v, off);
    if (lane == 0) {
        eg[wid] = expf(v + b_gate[0]);
        counts[wid] = 0;
    }
}

// ---------------------------------------------------------------------------
// K2: histogram of destination nodes
// ---------------------------------------------------------------------------
__global__ void count_kernel(const int* __restrict__ row,
                             int* __restrict__ counts, int nE) {
    int e = blockIdx.x * blockDim.x + threadIdx.x;
    if (e < nE) atomicAdd(&counts[row[e]], 1);
}

// ---------------------------------------------------------------------------
// K3: exclusive scan of counts -> offs (and cursor copy). Single block.
// ---------------------------------------------------------------------------
__global__ void scan_kernel(const int* __restrict__ counts,
                            int* __restrict__ offs,
                            int* __restrict__ cursor, int n, int nE) {
    const int T = 1024;
    __shared__ int lds[T];
    int tid = threadIdx.x;
    int per = (n + T - 1) / T;
    int s = tid * per;
    int e = s + per; if (e > n) e = n;
    int sum = 0;
    for (int i = s; i < e; i++) sum += counts[i];
    lds[tid] = sum;
    __syncthreads();
    for (int off = 1; off < T; off <<= 1) {
        int t = (tid >= off) ? lds[tid - off] : 0;
        __syncthreads();
        lds[tid] += t;
        __syncthreads();
    }
    int run = lds[tid] - sum;   // exclusive prefix of strips
    for (int i = s; i < e; i++) {
        offs[i] = run;
        cursor[i] = run;
        run += counts[i];
    }
    if (tid == 0) offs[n] = nE;
}

// ---------------------------------------------------------------------------
// K4: counting-sort scatter: edata[p] = {src_col, exp_gate(src)} packed 8B
// ---------------------------------------------------------------------------
__global__ void scatter_kernel(const int* __restrict__ row,
                               const int* __restrict__ col,
                               const float* __restrict__ eg,
                               int* __restrict__ cursor,
                               int2* __restrict__ edata, int nE) {
    int e = blockIdx.x * blockDim.x + threadIdx.x;
    if (e < nE) {
        int r = row[e];
        int c = col[e];
        int p = atomicAdd(&cursor[r], 1);
        edata[p] = make_int2(c, __float_as_int(eg[c]));   // one 8B scattered store
    }
}

// ---------------------------------------------------------------------------
// K5: per-node weighted aggregation, ONE pass:
//     agg[n] = (sum_e ev_e * x[col_e]) / (sum_e ev_e),  sArr[n] = s (1 or 0)
//     One wave/node. float4 loads, 2 edges per wave-instruction (32 lanes
//     each), unroll 4 -> 4 independent 1KB row-loads in flight.
// ---------------------------------------------------------------------------
__global__ void agg_kernel(const float* __restrict__ x,
                           const int* __restrict__ offs,
                           const int2* __restrict__ edata,
                           float* __restrict__ agg,
                           float* __restrict__ sArr, int n) {
    int wid  = (int)((blockIdx.x * blockDim.x + threadIdx.x) >> 6);
    int lane = threadIdx.x & 63;
    if (wid >= n) return;
    int beg = offs[wid];
    int end = offs[wid + 1];
    int half = lane >> 5;      // which edge of the pair
    int sl   = lane & 31;      // float4 slot within the row

    float4 acc = make_float4(0.f, 0.f, 0.f, 0.f);
    float denom = 0.f;

    for (int base = beg; base < end; base += 64) {
        int j = base + lane;
        int2 ed = (j < end) ? edata[j] : make_int2(0, 0);  // pad: col 0, w bits 0
        float ev = __int_as_float(ed.y);                   // 0.0f for pad
        // denominator contribution (butterfly -> all lanes hold chunk sum)
        float evs = ev;
        #pragma unroll
        for (int off = 32; off; off >>= 1) evs += __shfl_xor(evs, off);
        denom += evs;

        int m  = end - base; if (m > 64) m = 64;
        int mp = (m + 1) & ~1;                 // pad pair
        #pragma unroll 4
        for (int t = 0; t < mp; t += 2) {
            int   src = t + half;
            int   ct  = __shfl(ed.x, src);     // edge (t+half)'s source node
            float w   = __shfl(ev,  src);      // its weight (0 if padded)
            const float4* xr = (const float4*)(x + (size_t)ct * DIM);
            float4 xv = xr[sl];                // 32 lanes x 16B = one 512B row
            acc.x += w * xv.x;
            acc.y += w * xv.y;
            acc.z += w * xv.z;
            acc.w += w * xv.w;
        }
    }
    float inv = 1.f / (denom + 1e-16f);
    // fold the two half-wave accumulators together
    acc.x += __shfl_xor(acc.x, 32);
    acc.y += __shfl_xor(acc.y, 32);
    acc.z += __shfl_xor(acc.z, 32);
    acc.w += __shfl_xor(acc.w, 32);
    if (half == 0) {
        float4 r;
        r.x = acc.x * inv; r.y = acc.y * inv;
        r.z = acc.z * inv; r.w = acc.w * inv;
        ((float4*)(agg + (size_t)wid * DIM))[sl] = r;
    }
    if (lane == 0) sArr[wid] = denom * inv;    // ~1, or 0 for empty segment
}

// ---------------------------------------------------------------------------
// K6: fold linear layers:  WcT[i*128+o] = sum_k W_out[o][k]*W_lin[k][i]
//     bc[o] = sum_k W_out[o][k]*b_lin[k]
// ---------------------------------------------------------------------------
__global__ void wc_kernel(const float* __restrict__ W_out,
                          const float* __restrict__ W_lin,
                          const float* __restrict__ b_lin,
                          float* __restrict__ WcT,
                          float* __restrict__ bc) {
    int o = blockIdx.x;
    int i = threadIdx.x;
    __shared__ float wrow[DIM];
    __shared__ float red[DIM];
    wrow[i] = W_out[o * DIM + i];
    __syncthreads();
    float acc = 0.f;
    #pragma unroll 8
    for (int k = 0; k < DIM; k++) acc += wrow[k] * W_lin[k * DIM + i];
    WcT[i * DIM + o] = acc;
    red[i] = wrow[i] * b_lin[i];
    __syncthreads();
    for (int off = 64; off; off >>= 1) {
        if (i < off) red[i] += red[i + off];
        __syncthreads();
    }
    if (i == 0) bc[o] = red[0];
}

// ---------------------------------------------------------------------------
// K7: out[n][o] = sum_i agg[n][i]*Wc[o][i] + s[n]*bc[o] + b_out[o]
//     16 nodes per block (2 groups x 8) to amortize the 64KB WcT reads.
// ---------------------------------------------------------------------------
__global__ void out_kernel(const float* __restrict__ agg,
                           const float* __restrict__ sArr,
                           const float* __restrict__ WcT,
                           const float* __restrict__ bc,
                           const float* __restrict__ b_out,
                           float* __restrict__ out, int n) {
    __shared__ float aggL[2][8][DIM];
    __shared__ float sL[2][8];
    int grp = threadIdx.x >> 7;     // 0 or 1
    int o   = threadIdx.x & 127;
    float bcv = bc[o];
    float bov = b_out[o];

    int node0 = blockIdx.x * 16 + grp * 8;
    #pragma unroll
    for (int t = 0; t < 8; t++) {
        int node = node0 + t;
        aggL[grp][t][o] = (node < n) ? agg[(size_t)node * DIM + o] : 0.f;
    }
    if (o < 8) {
        int node = node0 + o;
        sL[grp][o] = (node < n) ? sArr[node] : 0.f;
    }
    __syncthreads();

    float a[8];
    #pragma unroll
    for (int t = 0; t < 8; t++) a[t] = 0.f;
    #pragma unroll 4
    for (int i = 0; i < DIM; i++) {
        float w = WcT[i * DIM + o];     // coalesced, L2-resident
        #pragma unroll
        for (int t = 0; t < 8; t++) a[t] += w * aggL[grp][t][i];
    }
    #pragma unroll
    for (int t = 0; t < 8; t++) {
        int node = node0 + t;
        if (node < n) out[(size_t)node * DIM + o] = a[t] + sL[grp][t] * bcv + bov;
    }
}

// ---------------------------------------------------------------------------
extern "C" void kernel_launch(void* const* d_in, const int* in_sizes, int n_in,
                              void* d_out, int out_size, void* d_ws, size_t ws_size,
                              hipStream_t stream) {
    const float* x      = (const float*)d_in[0];
    const int*   eidx   = (const int*)d_in[1];   // [2, nE] int
    const float* W_lin  = (const float*)d_in[3];
    const float* b_lin  = (const float*)d_in[4];
    const float* W_gate = (const float*)d_in[5];
    const float* b_gate = (const float*)d_in[6];
    const float* W_out  = (const float*)d_in[7];
    const float* b_out  = (const float*)d_in[8];
    float* out = (float*)d_out;

    const int n  = N_NODES_C;
    const int nE = N_EDGES_C;
    const int* row = eidx;
    const int* col = eidx + nE;

    char* ws = (char*)d_ws;
    size_t off = 0;
    auto carve = [&](size_t bytes) -> char* {
        char* p = ws + off;
        off += (bytes + 255) & ~(size_t)255;
        return p;
    };
    float* eg     = (float*)carve((size_t)n * 4);
    int*   counts = (int*)  carve((size_t)n * 4);
    int*   offs   = (int*)  carve((size_t)(n + 1) * 4);
    int*   cursor = (int*)  carve((size_t)(n + 1) * 4);
    float* sArr   = (float*)carve((size_t)n * 4);
    int2*  edata  = (int2*) carve((size_t)nE * 8);
    float* agg    = (float*)carve((size_t)n * DIM * 4);
    float* WcT    = (float*)carve((size_t)DIM * DIM * 4);
    float* bc     = (float*)carve((size_t)DIM * 4);

    const int edgeBlocks = (nE + 255) / 256;          // 2500
    const int waveBlocks = ((n * 64) + 255) / 256;    // 2500

    gate_kernel   <<<waveBlocks, 256, 0, stream>>>(x, W_gate, b_gate, eg, counts, n);
    count_kernel  <<<edgeBlocks, 256, 0, stream>>>(row, counts, nE);
    scan_kernel   <<<1, 1024, 0, stream>>>(counts, offs, cursor, n, nE);
    scatter_kernel<<<edgeBlocks, 256, 0, stream>>>(row, col, eg, cursor, edata, nE);
    agg_kernel    <<<waveBlocks, 256, 0, stream>>>(x, offs, edata, agg, sArr, n);
    wc_kernel     <<<DIM, DIM, 0, stream>>>(W_out, W_lin, b_lin, WcT, bc);
    out_kernel    <<<(n + 15) / 16, 256, 0, stream>>>(agg, sArr, WcT, bc, b_out, out, n);
}

// Round 3
// 106.423 us; speedup vs baseline: 1.6312x; 1.4505x over previous
//
#include <hip/hip_runtime.h>
#include <math.h>

#define N_NODES_C 10000
#define N_EDGES_C 640000
#define DIM 128
#define NB 157              // ceil(10000/64) buckets of 64 nodes
#define CHUNK 2048          // edges per bscatter block
#define KPT 8               // edges per thread in bscatter (CHUNK/256)

// ---------------------------------------------------------------------------
// K1: per-node gate exp:  eg[i] = exp(x[i] . w_gate + b_gate)
// ---------------------------------------------------------------------------
__global__ void gate_kernel(const float* __restrict__ x,
                            const float* __restrict__ w_gate,
                            const float* __restrict__ b_gate,
                            float* __restrict__ eg, int n) {
    int wid  = (int)((blockIdx.x * blockDim.x + threadIdx.x) >> 6);
    int lane = threadIdx.x & 63;
    if (wid >= n) return;
    const float2* xr = (const float2*)(x + (size_t)wid * DIM);
    const float2* wg = (const float2*)w_gate;
    float2 a = xr[lane];
    float2 b = wg[lane];
    float v = a.x * b.x + a.y * b.y;
    #pragma unroll
    for (int off = 32; off; off >>= 1) v += __shfl_xor(v, off);
    if (lane == 0) eg[wid] = expf(v + b_gate[0]);
}

// ---------------------------------------------------------------------------
// K2: bucket histogram (bucket = row>>6). LDS-combined, few global atomics.
// ---------------------------------------------------------------------------
__global__ void bcount_kernel(const int* __restrict__ row,
                              int* __restrict__ bucket_counts, int nE) {
    __shared__ int h[NB];
    for (int i = threadIdx.x; i < NB; i += blockDim.x) h[i] = 0;
    __syncthreads();
    for (int e = blockIdx.x * blockDim.x + threadIdx.x; e < nE;
         e += gridDim.x * blockDim.x)
        atomicAdd(&h[row[e] >> 6], 1);
    __syncthreads();
    for (int i = threadIdx.x; i < NB; i += blockDim.x)
        if (h[i]) atomicAdd(&bucket_counts[i], h[i]);
}

// ---------------------------------------------------------------------------
// K3: scan 157 bucket counts -> bucket_base[NB+1], bucket_cursor[NB]
// ---------------------------------------------------------------------------
__global__ void bscan_kernel(const int* __restrict__ bucket_counts,
                             int* __restrict__ bucket_base,
                             int* __restrict__ bucket_cursor, int nE) {
    __shared__ int lds[256];
    int tid = threadIdx.x;
    int v = (tid < NB) ? bucket_counts[tid] : 0;
    lds[tid] = v;
    __syncthreads();
    for (int off = 1; off < 256; off <<= 1) {
        int t = (tid >= off) ? lds[tid - off] : 0;
        __syncthreads();
        lds[tid] += t;
        __syncthreads();
    }
    int excl = lds[tid] - v;
    if (tid < NB) {
        bucket_base[tid]   = excl;
        bucket_cursor[tid] = excl;
    }
    if (tid == 0) bucket_base[NB] = nE;
}

// ---------------------------------------------------------------------------
// K4: bin edges by bucket. Per-block LDS histogram -> one global atomic per
//     (block,bucket) -> ~104B contiguous runs instead of random 8B stores.
//     Record: { (local_node<<16) | col , bits(exp_gate[col]) }
// ---------------------------------------------------------------------------
__global__ void bscatter_kernel(const int* __restrict__ row,
                                const int* __restrict__ col,
                                const float* __restrict__ eg,
                                int* __restrict__ bucket_cursor,
                                int2* __restrict__ edata_b, int nE) {
    __shared__ int hist[NB];
    __shared__ int lbase[NB];
    int tid = threadIdx.x;
    for (int i = tid; i < NB; i += blockDim.x) hist[i] = 0;
    __syncthreads();

    int start = blockIdx.x * CHUNK;
    int bkt[KPT], rnk[KPT], cl[KPT];
    #pragma unroll
    for (int k = 0; k < KPT; k++) {
        int e = start + k * blockDim.x + tid;   // coalesced
        if (e < nE) {
            int r = row[e];
            int b = r >> 6;
            bkt[k] = b;
            cl[k]  = ((r & 63) << 16) | col[e];
            rnk[k] = atomicAdd(&hist[b], 1);
        } else {
            bkt[k] = -1; rnk[k] = 0; cl[k] = 0;
        }
    }
    __syncthreads();
    for (int i = tid; i < NB; i += blockDim.x)
        lbase[i] = hist[i] ? atomicAdd(&bucket_cursor[i], hist[i]) : 0;
    __syncthreads();
    #pragma unroll
    for (int k = 0; k < KPT; k++) {
        if (bkt[k] >= 0) {
            int p = lbase[bkt[k]] + rnk[k];
            int c = cl[k] & 0xFFFF;
            edata_b[p] = make_int2(cl[k], __float_as_int(eg[c]));
        }
    }
}

// ---------------------------------------------------------------------------
// K5: per-bucket counting sort over 64 local nodes. One block per bucket.
//     All writes land in this block's own bucket region (single XCD -> L2
//     write-combining). Also emits per-node CSR offs.
// ---------------------------------------------------------------------------
__global__ void bsort_kernel(const int2* __restrict__ edata_b,
                             const int* __restrict__ bucket_base,
                             int* __restrict__ offs,
                             int2* __restrict__ edata, int n, int nE) {
    __shared__ int cnt[64];
    __shared__ int cur[64];
    int b    = blockIdx.x;
    int tid  = threadIdx.x;
    int base = bucket_base[b];
    int endB = bucket_base[b + 1];

    if (tid < 64) cnt[tid] = 0;
    __syncthreads();
    for (int j = base + tid; j < endB; j += blockDim.x)
        atomicAdd(&cnt[edata_b[j].x >> 16], 1);
    __syncthreads();

    if (tid < 64) {                       // one-wave exclusive scan of 64 cnts
        int v = cnt[tid];
        int s = v;
        #pragma unroll
        for (int off = 1; off < 64; off <<= 1) {
            int t = __shfl_up(s, off);
            if (tid >= off) s += t;
        }
        int excl = s - v;
        cur[tid] = base + excl;
        int node = (b << 6) + tid;
        if (node < n) offs[node] = base + excl;
    }
    if (b == 0 && tid == 0) offs[n] = nE;
    __syncthreads();

    for (int j = base + tid; j < endB; j += blockDim.x) {
        int2 rec = edata_b[j];
        int p = atomicAdd(&cur[rec.x >> 16], 1);
        edata[p] = make_int2(rec.x & 0xFFFF, rec.y);
    }
}

// ---------------------------------------------------------------------------
// K6: per-node weighted aggregation, one pass.
//     agg[n] = (sum_e ev_e * x[col_e]) / (sum_e ev_e),  sArr[n] = 1 or 0.
// ---------------------------------------------------------------------------
__global__ void agg_kernel(const float* __restrict__ x,
                           const int* __restrict__ offs,
                           const int2* __restrict__ edata,
                           float* __restrict__ agg,
                           float* __restrict__ sArr, int n) {
    int wid  = (int)((blockIdx.x * blockDim.x + threadIdx.x) >> 6);
    int lane = threadIdx.x & 63;
    if (wid >= n) return;
    int beg = offs[wid];
    int end = offs[wid + 1];
    int half = lane >> 5;
    int sl   = lane & 31;

    float4 acc = make_float4(0.f, 0.f, 0.f, 0.f);
    float denom = 0.f;

    for (int base = beg; base < end; base += 64) {
        int j = base + lane;
        int2 ed = (j < end) ? edata[j] : make_int2(0, 0);
        float ev = __int_as_float(ed.y);
        float evs = ev;
        #pragma unroll
        for (int off = 32; off; off >>= 1) evs += __shfl_xor(evs, off);
        denom += evs;

        int m  = end - base; if (m > 64) m = 64;
        int mp = (m + 1) & ~1;
        #pragma unroll 4
        for (int t = 0; t < mp; t += 2) {
            int   src = t + half;
            int   ct  = __shfl(ed.x, src);
            float w   = __shfl(ev,  src);
            const float4* xr = (const float4*)(x + (size_t)ct * DIM);
            float4 xv = xr[sl];
            acc.x += w * xv.x;
            acc.y += w * xv.y;
            acc.z += w * xv.z;
            acc.w += w * xv.w;
        }
    }
    float inv = 1.f / (denom + 1e-16f);
    acc.x += __shfl_xor(acc.x, 32);
    acc.y += __shfl_xor(acc.y, 32);
    acc.z += __shfl_xor(acc.z, 32);
    acc.w += __shfl_xor(acc.w, 32);
    if (half == 0) {
        float4 r;
        r.x = acc.x * inv; r.y = acc.y * inv;
        r.z = acc.z * inv; r.w = acc.w * inv;
        ((float4*)(agg + (size_t)wid * DIM))[sl] = r;
    }
    if (lane == 0) sArr[wid] = denom * inv;
}

// ---------------------------------------------------------------------------
// K7: fold linear layers: WcT[i*128+o] = sum_k W_out[o][k]*W_lin[k][i]
// ---------------------------------------------------------------------------
__global__ void wc_kernel(const float* __restrict__ W_out,
                          const float* __restrict__ W_lin,
                          const float* __restrict__ b_lin,
                          float* __restrict__ WcT,
                          float* __restrict__ bc) {
    int o = blockIdx.x;
    int i = threadIdx.x;
    __shared__ float wrow[DIM];
    __shared__ float red[DIM];
    wrow[i] = W_out[o * DIM + i];
    __syncthreads();
    float acc = 0.f;
    #pragma unroll 8
    for (int k = 0; k < DIM; k++) acc += wrow[k] * W_lin[k * DIM + i];
    WcT[i * DIM + o] = acc;
    red[i] = wrow[i] * b_lin[i];
    __syncthreads();
    for (int off = 64; off; off >>= 1) {
        if (i < off) red[i] += red[i + off];
        __syncthreads();
    }
    if (i == 0) bc[o] = red[0];
}

// ---------------------------------------------------------------------------
// K8: out[n][o] = sum_i agg[n][i]*Wc[o][i] + s[n]*bc[o] + b_out[o]
// ---------------------------------------------------------------------------
__global__ void out_kernel(const float* __restrict__ agg,
                           const float* __restrict__ sArr,
                           const float* __restrict__ WcT,
                           const float* __restrict__ bc,
                           const float* __restrict__ b_out,
                           float* __restrict__ out, int n) {
    __shared__ float aggL[2][8][DIM];
    __shared__ float sL[2][8];
    int grp = threadIdx.x >> 7;
    int o   = threadIdx.x & 127;
    float bcv = bc[o];
    float bov = b_out[o];

    int node0 = blockIdx.x * 16 + grp * 8;
    #pragma unroll
    for (int t = 0; t < 8; t++) {
        int node = node0 + t;
        aggL[grp][t][o] = (node < n) ? agg[(size_t)node * DIM + o] : 0.f;
    }
    if (o < 8) {
        int node = node0 + o;
        sL[grp][o] = (node < n) ? sArr[node] : 0.f;
    }
    __syncthreads();

    float a[8];
    #pragma unroll
    for (int t = 0; t < 8; t++) a[t] = 0.f;
    #pragma unroll 4
    for (int i = 0; i < DIM; i++) {
        float w = WcT[i * DIM + o];
        #pragma unroll
        for (int t = 0; t < 8; t++) a[t] += w * aggL[grp][t][i];
    }
    #pragma unroll
    for (int t = 0; t < 8; t++) {
        int node = node0 + t;
        if (node < n) out[(size_t)node * DIM + o] = a[t] + sL[grp][t] * bcv + bov;
    }
}

// ---------------------------------------------------------------------------
extern "C" void kernel_launch(void* const* d_in, const int* in_sizes, int n_in,
                              void* d_out, int out_size, void* d_ws, size_t ws_size,
                              hipStream_t stream) {
    const float* x      = (const float*)d_in[0];
    const int*   eidx   = (const int*)d_in[1];
    const float* W_lin  = (const float*)d_in[3];
    const float* b_lin  = (const float*)d_in[4];
    const float* W_gate = (const float*)d_in[5];
    const float* b_gate = (const float*)d_in[6];
    const float* W_out  = (const float*)d_in[7];
    const float* b_out  = (const float*)d_in[8];
    float* out = (float*)d_out;

    const int n  = N_NODES_C;
    const int nE = N_EDGES_C;
    const int* row = eidx;
    const int* col = eidx + nE;

    char* ws = (char*)d_ws;
    size_t off = 0;
    auto carve = [&](size_t bytes) -> char* {
        char* p = ws + off;
        off += (bytes + 255) & ~(size_t)255;
        return p;
    };
    float* eg            = (float*)carve((size_t)n * 4);
    int*   offs          = (int*)  carve((size_t)(n + 1) * 4);
    float* sArr          = (float*)carve((size_t)n * 4);
    int*   bucket_counts = (int*)  carve((size_t)NB * 4);
    int*   bucket_base   = (int*)  carve((size_t)(NB + 1) * 4);
    int*   bucket_cursor = (int*)  carve((size_t)NB * 4);
    int2*  edata         = (int2*) carve((size_t)nE * 8);
    // edata_b (5.12MB) aliases agg (5.12MB): edata_b fully consumed by
    // bsort before agg_kernel writes agg — stream-ordered, safe.
    char*  shared_region = carve((size_t)nE * 8);
    int2*  edata_b       = (int2*)shared_region;
    float* agg           = (float*)shared_region;
    float* WcT           = (float*)carve((size_t)DIM * DIM * 4);
    float* bc            = (float*)carve((size_t)DIM * 4);

    const int waveBlocks    = ((n * 64) + 255) / 256;     // 2500
    const int scatterBlocks = (nE + CHUNK - 1) / CHUNK;   // 313

    hipMemsetAsync(bucket_counts, 0, (size_t)NB * 4, stream);
    gate_kernel    <<<waveBlocks, 256, 0, stream>>>(x, W_gate, b_gate, eg, n);
    bcount_kernel  <<<512, 256, 0, stream>>>(row, bucket_counts, nE);
    bscan_kernel   <<<1, 256, 0, stream>>>(bucket_counts, bucket_base, bucket_cursor, nE);
    bscatter_kernel<<<scatterBlocks, 256, 0, stream>>>(row, col, eg, bucket_cursor, edata_b, nE);
    bsort_kernel   <<<NB, 256, 0, stream>>>(edata_b, bucket_base, offs, edata, n, nE);
    agg_kernel     <<<waveBlocks, 256, 0, stream>>>(x, offs, edata, agg, sArr, n);
    wc_kernel      <<<DIM, DIM, 0, stream>>>(W_out, W_lin, b_lin, WcT, bc);
    out_kernel     <<<(n + 15) / 16, 256, 0, stream>>>(agg, sArr, WcT, bc, b_out, out, n);
}